// Round 9
// baseline (928.157 us; speedup 1.0000x reference)
//
#include <hip/hip_runtime.h>
#include <hip/hip_bf16.h>

#define N_TOK 2048
#define HIDDEN 5120
#define HEAD_DIM 128
#define HQ 40
#define HKV 8
#define QKV_OUT 7208
#define Q_SIZE 5120
#define KV_SIZE 1024

typedef __attribute__((ext_vector_type(8))) short bf16x8;
typedef __attribute__((ext_vector_type(4))) float f32x4;
typedef __attribute__((ext_vector_type(4))) unsigned short us4;

__device__ inline unsigned short f2bf(float f) {
    return __builtin_bit_cast(unsigned short, __float2bfloat16(f));
}
__device__ inline float bf2f(unsigned short s) {
    unsigned u = ((unsigned)s) << 16;
    return __builtin_bit_cast(float, u);
}
__device__ inline f32x4 mfma16(bf16x8 a, bf16x8 b, f32x4 c) {
    return __builtin_amdgcn_mfma_f32_16x16x32_bf16(a, b, c, 0, 0, 0);
}
__device__ inline void gl16(const void* g, void* l) {
    __builtin_amdgcn_global_load_lds((__attribute__((address_space(1))) void*)g,
                                     (__attribute__((address_space(3))) void*)l, 16, 0, 0);
}

// ---------------- sort tokens by modality (stable) ----------------
__global__ void k_sort(const int* __restrict__ mids_raw, int* __restrict__ meta,
                       int* __restrict__ perm) {
    int l = threadIdx.x;  // 64 threads, 1 wave
    int oddnz = 0;
    for (int c = 0; c < 32; ++c) {
        int idx = c * 64 + l;
        int v = mids_raw[idx];
        if ((idx & 1) && v != 0) oddnz = 1;
    }
    bool is64 = (__ballot(oddnz) == 0ULL);
    int c0 = 0, c1 = 0;
    for (int c = 0; c < 32; ++c) {
        int i = c * 64 + l;
        int m = is64 ? mids_raw[2 * i] : mids_raw[i];
        c0 += (m == 0); c1 += (m == 1);
    }
    for (int o = 32; o; o >>= 1) { c0 += __shfl_xor(c0, o); c1 += __shfl_xor(c1, o); }
    if (l == 0) { meta[0] = 0; meta[1] = c0; meta[2] = c0 + c1; meta[3] = N_TOK; }
    int r0 = 0, r1 = c0, r2 = c0 + c1;
    unsigned long long below = (1ULL << l) - 1ULL;
    for (int c = 0; c < 32; ++c) {
        int i = c * 64 + l;
        int m = is64 ? mids_raw[2 * i] : mids_raw[i];
        unsigned long long b0 = __ballot(m == 0), b1 = __ballot(m == 1), b2 = __ballot(m == 2);
        int pos = (m == 0) ? r0 + __popcll(b0 & below)
                : (m == 1) ? r1 + __popcll(b1 & below)
                           : r2 + __popcll(b2 & below);
        perm[pos] = i;
        r0 += __popcll(b0); r1 += __popcll(b1); r2 += __popcll(b2);
    }
}

// ---------------- pre-norm ----------------
__global__ __launch_bounds__(256) void k_prenorm(const float* __restrict__ hidden,
        const float* __restrict__ pnw, const int* __restrict__ meta,
        const int* __restrict__ perm, unsigned short* __restrict__ h) {
    int i = blockIdx.x;
    int m = (i >= meta[1]) + (i >= meta[2]);
    int t = perm[i];
    const float4* x = (const float4*)(hidden + (size_t)t * HIDDEN);
    const float4* wv = (const float4*)(pnw + (size_t)m * HIDDEN);
    int tid = threadIdx.x;
    float4 xv[5];
    float ss = 0.f;
#pragma unroll
    for (int j = 0; j < 5; ++j) {
        xv[j] = x[tid + j * 256];
        ss += xv[j].x * xv[j].x + xv[j].y * xv[j].y + xv[j].z * xv[j].z + xv[j].w * xv[j].w;
    }
    for (int o = 32; o; o >>= 1) ss += __shfl_xor(ss, o);
    __shared__ float red[4];
    if ((tid & 63) == 0) red[tid >> 6] = ss;
    __syncthreads();
    float rms = rsqrtf((red[0] + red[1] + red[2] + red[3]) * (1.f / HIDDEN) + 1e-6f);
    us4* dst = (us4*)(h + (size_t)i * HIDDEN);
#pragma unroll
    for (int j = 0; j < 5; ++j) {
        float4 w = wv[tid + j * 256];
        us4 o4;
        o4.x = f2bf(xv[j].x * rms * (w.x + 1.f));
        o4.y = f2bf(xv[j].y * rms * (w.y + 1.f));
        o4.z = f2bf(xv[j].z * rms * (w.z + 1.f));
        o4.w = f2bf(xv[j].w * rms * (w.w + 1.f));
        dst[tid + j * 256] = o4;
    }
}

// ------- 256x128 MoE GEMM, 2-deep counted-vmcnt pipeline, fused fp32->bf16 B -------
// C[i,j] = sum_k A[i,k]*B[m,j,k]; A bf16 (gl16, pre-swizzled source), B fp32 ->
// regs -> bf16 ds_write (swizzled). 8 waves (4Mx2N of 64x64), BK=64, 3 LDS bufs
// (48 KiB each, 144 KiB dynamic). Per wave per batch: 4 gl16 + 4 float4 = 8 VMEM.
// Steady state: 2 batches in flight; per K-step wait vmcnt(8) (batch kt done,
// kt+1 still flying) -> BWRITE -> lgkmcnt(0) -> s_barrier -> COMPUTE -> STAGE(kt+2).
// Never drains vmcnt to 0 inside the loop (catalog T4).
template <int NOUT, bool SCATTER>
__global__ __launch_bounds__(512, 2) void k_gemm(
        const unsigned short* __restrict__ A, const float* __restrict__ Bw,
        unsigned short* __restrict__ outB, float* __restrict__ outF,
        const int* __restrict__ meta, const int* __restrict__ perm,
        int nx, int ny) {
    extern __shared__ char smem[];  // 3 * 49152
    // bijective chunked XCD swizzle (m204); tx fastest -> same-panel blocks co-XCD
    int nwg = nx * ny * 3;
    int bid = blockIdx.x;
    int xcd = bid & 7, o = bid >> 3;
    int q = nwg >> 3, r = nwg & 7;
    int swz = (xcd < r ? xcd * (q + 1) : r * (q + 1) + (xcd - r) * q) + o;
    int mz = swz / (nx * ny);
    int rest = swz - mz * (nx * ny);
    int ty = rest / nx, tx = rest - ty * nx;

    int rowS = meta[mz], rowE = meta[mz + 1];
    int row0 = rowS + tx * 256;
    if (row0 >= rowE) return;
    int col0 = ty * 128;
    const float* Bm = Bw + (size_t)mz * NOUT * HIDDEN;

    int tid = threadIdx.x, l = tid & 63, w = tid >> 6;
    int wr = (w >> 1) * 64, wc = (w & 1) * 64;

    f32x4 acc[4][4] = {};

    // A: tile 256 rows x 64 K bf16 (32 KiB). Round j (0..3) covers rows 64j..+63;
    // lane -> row 64j+8w+lr, chunk lc (16B). Source pre-swizzled lc^lr.
    const int lr = l >> 3, lc = l & 7;
    const int sch = (lc ^ lr) * 8;  // shorts
    const unsigned short* ag[4];
#pragma unroll
    for (int j = 0; j < 4; ++j) {
        int ar = row0 + 64 * j + 8 * w + lr;
        if (ar > rowE - 1) ar = rowE - 1;
        ag[j] = A + (size_t)ar * HIDDEN + sch;
    }
    // B: tile 128 rows x 64 K fp32 -> bf16 (16 KiB). Round j (0..1) covers rows
    // 64j..+63; lane -> row 64j+8w+lr, K-chunk lc (8 floats).
    const float* bg[2];
    int brow[2];
#pragma unroll
    for (int j = 0; j < 2; ++j) {
        int bc = col0 + 64 * j + 8 * w + lr;
        if (bc > NOUT - 1) bc = NOUT - 1;
        bg[j] = Bm + (size_t)bc * HIDDEN + lc * 8;
        brow[j] = 64 * j + 8 * w + lr;
    }

    float4 bregA[2][2], bregB[2][2];
    auto STAGE = [&](float4 (&br)[2][2], int buf, int kk) {
        char* ab = smem + buf * 49152 + w * 1024;
#pragma unroll
        for (int j = 0; j < 4; ++j) gl16(ag[j] + kk, ab + j * 8192);
#pragma unroll
        for (int j = 0; j < 2; ++j) {
            br[j][0] = *(const float4*)(bg[j] + kk);
            br[j][1] = *(const float4*)(bg[j] + kk + 4);
        }
        __builtin_amdgcn_sched_barrier(0);  // pin batch boundary (vmcnt counting)
    };
    auto BWRITE = [&](float4 (&br)[2][2], int buf) {
#pragma unroll
        for (int j = 0; j < 2; ++j) {
            bf16x8 pk;
            pk[0] = (short)f2bf(br[j][0].x); pk[1] = (short)f2bf(br[j][0].y);
            pk[2] = (short)f2bf(br[j][0].z); pk[3] = (short)f2bf(br[j][0].w);
            pk[4] = (short)f2bf(br[j][1].x); pk[5] = (short)f2bf(br[j][1].y);
            pk[6] = (short)f2bf(br[j][1].z); pk[7] = (short)f2bf(br[j][1].w);
            *(bf16x8*)(smem + buf * 49152 + 32768 + brow[j] * 128 +
                       ((lc * 16) ^ ((brow[j] & 7) << 4))) = pk;
        }
    };
    auto COMPUTE = [&](int buf) {
        char* baseA = smem + buf * 49152;
        char* baseB = baseA + 32768;
#pragma unroll
        for (int ks = 0; ks < 2; ++ks) {
            bf16x8 af[4], bfm[4];
#pragma unroll
            for (int mi = 0; mi < 4; ++mi) {
                int row = wr + mi * 16 + (l & 15);
                af[mi] = *(const bf16x8*)(baseA + row * 128 +
                            ((ks * 64 + (l >> 4) * 16) ^ ((row & 7) << 4)));
            }
#pragma unroll
            for (int ni = 0; ni < 4; ++ni) {
                int row = wc + ni * 16 + (l & 15);
                bfm[ni] = *(const bf16x8*)(baseB + row * 128 +
                            ((ks * 64 + (l >> 4) * 16) ^ ((row & 7) << 4)));
            }
#pragma unroll
            for (int mi = 0; mi < 4; ++mi)
#pragma unroll
                for (int ni = 0; ni < 4; ++ni)
                    acc[mi][ni] = mfma16(af[mi], bfm[ni], acc[mi][ni]);
        }
    };

    int bufc = 0;
    auto BODY = [&](float4 (&br)[2][2], int stage_kt, bool last) {
        if (last) asm volatile("s_waitcnt vmcnt(0)" ::: "memory");
        else      asm volatile("s_waitcnt vmcnt(8)" ::: "memory");
        __builtin_amdgcn_sched_barrier(0);
        BWRITE(br, bufc);
        asm volatile("s_waitcnt lgkmcnt(0)" ::: "memory");
        __builtin_amdgcn_sched_barrier(0);
        __builtin_amdgcn_s_barrier();
        __builtin_amdgcn_sched_barrier(0);
        COMPUTE(bufc);
        if (stage_kt < HIDDEN / 64) {
            int bs = bufc + 2; if (bs >= 3) bs -= 3;
            STAGE(br, bs, stage_kt * 64);
        }
        bufc = (bufc + 1 == 3) ? 0 : bufc + 1;
    };

    STAGE(bregA, 0, 0);
    STAGE(bregB, 1, 64);
#pragma unroll 1
    for (int kt = 0; kt < HIDDEN / 64; kt += 2) {
        BODY(bregA, kt + 2, false);
        BODY(bregB, kt + 3, kt + 3 >= HIDDEN / 64);
    }

    // epilogue: C/D layout col=lane&15, row=(lane>>4)*4+r
#pragma unroll
    for (int mi = 0; mi < 4; ++mi) {
        int rbase = row0 + wr + mi * 16 + ((l >> 4) << 2);
#pragma unroll
        for (int ni = 0; ni < 4; ++ni) {
            int col = col0 + wc + ni * 16 + (l & 15);
            if (col >= NOUT) continue;
#pragma unroll
            for (int rr = 0; rr < 4; ++rr) {
                int row = rbase + rr;
                if (row >= rowE) continue;
                if (SCATTER) {
                    int t = perm[row];
                    outF[(size_t)t * HIDDEN + col] = acc[mi][ni][rr];
                } else {
                    outB[(size_t)row * NOUT + col] = f2bf(acc[mi][ni][rr]);
                }
            }
        }
    }
}

// ---------------- qk-norm + rope + gate ----------------
// q is pre-scaled by log2(e)/sqrt(128) so attention uses exp2 directly.
__global__ __launch_bounds__(256) void k_qknorm(const unsigned short* __restrict__ qkv,
        const float* __restrict__ rope, const float* __restrict__ qnw,
        const float* __restrict__ knw, const int* __restrict__ meta,
        const int* __restrict__ perm, unsigned short* __restrict__ qb,
        unsigned short* __restrict__ kb, float* __restrict__ gate) {
    int i = blockIdx.x;
    int m = (i >= meta[1]) + (i >= meta[2]);
    int t = perm[i];
    int tid = threadIdx.x, w = tid >> 6, l = tid & 63;
    const unsigned short* base = qkv + (size_t)i * QKV_OUT;
    const float* rp = rope + (size_t)t * HEAD_DIM;
    const float qscale = 0.08838834764831845f * 1.4426950408889634f;  // log2e/sqrt(128)
    for (int hh = w; hh < 48; hh += 4) {
        bool isq = hh < 40;
        const unsigned short* src = base + (isq ? hh * 128 : Q_SIZE + (hh - 40) * 128);
        float x0 = bf2f(src[2 * l]), x1 = bf2f(src[2 * l + 1]);
        float ss = x0 * x0 + x1 * x1;
        for (int o = 32; o; o >>= 1) ss += __shfl_xor(ss, o);
        float rms = rsqrtf(ss * (1.f / 128.f) + 1e-6f);
        const float* nw = (isq ? qnw : knw) + m * 128;
        float y0 = x0 * rms * (nw[2 * l] + 1.f);
        float y1 = x1 * rms * (nw[2 * l + 1] + 1.f);
        float p0 = __shfl_xor(y0, 32);
        float p1 = __shfl_xor(y1, 32);
        float r0v, r1v;
        if (l < 32) {
            int d = 2 * l;
            r0v = y0 * rp[64 + d] - p0 * rp[d];
            r1v = y1 * rp[64 + d + 1] - p1 * rp[d + 1];
        } else {
            int d = 2 * l - 64;
            r0v = p0 * rp[d] + y0 * rp[64 + d];
            r1v = p1 * rp[d + 1] + y1 * rp[64 + d + 1];
        }
        if (isq) {
            r0v *= qscale; r1v *= qscale;
            unsigned short* dst = qb + (size_t)i * Q_SIZE + hh * 128 + 2 * l;
            dst[0] = f2bf(r0v); dst[1] = f2bf(r1v);
        } else {
            unsigned short* dst = kb + (size_t)i * KV_SIZE + (hh - 40) * 128 + 2 * l;
            dst[0] = f2bf(r0v); dst[1] = f2bf(r1v);
        }
    }
    if (tid < HQ) {
        float g = bf2f(base[Q_SIZE + 2 * KV_SIZE + tid]);
        gate[(size_t)i * HQ + tid] = 1.f / (1.f + expf(-g));
    }
}

// ---------------- transpose V ----------------
__global__ __launch_bounds__(256) void k_vtrans(const unsigned short* __restrict__ qkv,
                                                unsigned short* __restrict__ vT) {
    int t0 = blockIdx.x * 64, db = blockIdx.y * 64, kvh = blockIdx.z;
    __shared__ unsigned short tile[64][68];
    int tid = threadIdx.x;
    int tr = tid >> 2, seg = tid & 3;
    const unsigned short* src = qkv + (size_t)(t0 + tr) * QKV_OUT + Q_SIZE + KV_SIZE +
                                kvh * 128 + db + seg * 16;
    us4* drow = (us4*)&tile[tr][seg * 16];
#pragma unroll
    for (int q = 0; q < 4; ++q) drow[q] = ((const us4*)src)[q];
    __syncthreads();
    int dr = tid >> 2;
    unsigned short* dst = vT + ((size_t)kvh * 128 + db + dr) * N_TOK + t0 + seg * 16;
    unsigned short buf[16];
#pragma unroll
    for (int j = 0; j < 16; ++j) buf[j] = tile[seg * 16 + j][dr];
#pragma unroll
    for (int q = 0; q < 4; ++q) ((us4*)dst)[q] = ((us4*)buf)[q];
}

// ---------------- flash attention, fixed-max softmax ----------------
__global__ __launch_bounds__(256) void k_attn(
        const unsigned short* __restrict__ qb,
        const unsigned short* __restrict__ kb,
        const unsigned short* __restrict__ vT,
        const float* __restrict__ gate,
        unsigned short* __restrict__ og) {
    int qt = blockIdx.x, qh = blockIdx.y, kvh = qh / 5;
    int tid = threadIdx.x, w = tid >> 6, l = tid & 63;
    int q0 = qt * 128 + w * 32;
    __shared__ __align__(16) char smem[49152];
    char* Ks = smem;
    char* Vs = smem + 16384;
    char* Ps = smem + 32768 + w * 4096;

    bf16x8 qf[2][4];
#pragma unroll
    for (int mi = 0; mi < 2; ++mi)
#pragma unroll
        for (int ks = 0; ks < 4; ++ks)
            qf[mi][ks] = *(const bf16x8*)(qb + (size_t)(q0 + mi * 16 + (l & 15)) * Q_SIZE +
                                          qh * 128 + ks * 32 + (l >> 4) * 8);

    f32x4 oacc[2][8] = {};
    f32x4 psum[2] = {};

    int kr = tid >> 2, kseg = tid & 3;
    int vr = tid >> 1, vh2 = tid & 1;

#pragma unroll 1
    for (int kt = 0; kt < 32; ++kt) {
        int t0 = kt * 64;
        bf16x8 kv4[4], vv4[4];
        const unsigned short* ksrc = kb + (size_t)(t0 + kr) * KV_SIZE + kvh * 128 + kseg * 32;
        const unsigned short* vsrc = vT + ((size_t)kvh * 128 + vr) * N_TOK + t0 + vh2 * 32;
#pragma unroll
        for (int q = 0; q < 4; ++q) {
            kv4[q] = *(const bf16x8*)(ksrc + q * 8);
            vv4[q] = *(const bf16x8*)(vsrc + q * 8);
        }
        __syncthreads();
#pragma unroll
        for (int q = 0; q < 4; ++q) {
            *(bf16x8*)(Ks + kr * 256 + ((((kseg * 4 + q) * 16)) ^ ((kr & 7) << 4))) = kv4[q];
            *(bf16x8*)(Vs + vr * 128 + ((((vh2 * 4 + q) * 16)) ^ ((vr & 7) << 4))) = vv4[q];
        }
        __syncthreads();
        // S = Q K^T
        f32x4 s[2][4] = {};
#pragma unroll
        for (int ks = 0; ks < 4; ++ks) {
            bf16x8 kf[4];
#pragma unroll
            for (int ni = 0; ni < 4; ++ni) {
                int row = ni * 16 + (l & 15);
                kf[ni] = *(const bf16x8*)(Ks + row * 256 +
                            ((ks * 64 + (l >> 4) * 16) ^ ((row & 7) << 4)));
            }
#pragma unroll
            for (int mi = 0; mi < 2; ++mi)
#pragma unroll
                for (int ni = 0; ni < 4; ++ni)
                    s[mi][ni] = mfma16(qf[mi][ks], kf[ni], s[mi][ni]);
        }
        // p = exp2(s); per-lane row-sum accumulate; bf16 P to wave-private LDS.
#pragma unroll
        for (int mi = 0; mi < 2; ++mi)
#pragma unroll
            for (int ni = 0; ni < 4; ++ni) {
#pragma unroll
                for (int r = 0; r < 4; ++r) {
                    float p = exp2f(s[mi][ni][r]);
                    psum[mi][r] += p;
                    int qr = mi * 16 + ((l >> 4) << 2) + r;
                    int tcb = (ni * 16 + (l & 15)) * 2;
                    *(unsigned short*)(Ps + qr * 128 +
                        (tcb ^ (((qr >> 2) & 3) << 5))) = f2bf(p);
                }
            }
        // O += P V
#pragma unroll
        for (int ks = 0; ks < 2; ++ks) {
            bf16x8 pa[2];
#pragma unroll
            for (int mi = 0; mi < 2; ++mi) {
                int qr = mi * 16 + (l & 15);
                pa[mi] = *(const bf16x8*)(Ps + qr * 128 +
                            ((ks * 64 + (l >> 4) * 16) ^ (((qr >> 2) & 3) << 5)));
            }
#pragma unroll
            for (int nd = 0; nd < 8; ++nd) {
                int row = nd * 16 + (l & 15);
                bf16x8 vf = *(const bf16x8*)(Vs + row * 128 +
                            ((ks * 64 + (l >> 4) * 16) ^ ((row & 7) << 4)));
#pragma unroll
                for (int mi = 0; mi < 2; ++mi)
                    oacc[mi][nd] = mfma16(pa[mi], vf, oacc[mi][nd]);
            }
        }
    }
    // deferred row-sum reduce: rows live in 16-lane groups (same l>>4)
#pragma unroll
    for (int mi = 0; mi < 2; ++mi)
#pragma unroll
        for (int r = 0; r < 4; ++r) {
            float v = psum[mi][r];
            v += __shfl_xor(v, 1);
            v += __shfl_xor(v, 2);
            v += __shfl_xor(v, 4);
            v += __shfl_xor(v, 8);
            psum[mi][r] = v;
        }
#pragma unroll
    for (int mi = 0; mi < 2; ++mi)
#pragma unroll
        for (int r = 0; r < 4; ++r) {
            int row = q0 + mi * 16 + ((l >> 4) << 2) + r;
            float sc = (1.f / psum[mi][r]) * gate[(size_t)row * HQ + qh];
#pragma unroll
            for (int nd = 0; nd < 8; ++nd)
                og[(size_t)row * Q_SIZE + qh * 128 + nd * 16 + (l & 15)] =
                    f2bf(oacc[mi][nd][r] * sc);
        }
}

extern "C" void kernel_launch(void* const* d_in, const int* in_sizes, int n_in,
                              void* d_out, int out_size, void* d_ws, size_t ws_size,
                              hipStream_t stream) {
    const float* hidden = (const float*)d_in[0];
    const float* rope   = (const float*)d_in[1];
    const float* pnw    = (const float*)d_in[2];
    const float* qkvw   = (const float*)d_in[3];
    const float* qnw    = (const float*)d_in[4];
    const float* knw    = (const float*)d_in[5];
    const float* projw  = (const float*)d_in[6];
    const int*   mids   = (const int*)d_in[7];
    float* out = (float*)d_out;

    char* ws = (char*)d_ws;
    const size_t small_bytes = 16384 +
        (size_t)N_TOK * HIDDEN * 2 +      // h
        (size_t)N_TOK * QKV_OUT * 2 +     // qkv
        (size_t)N_TOK * Q_SIZE * 2 +      // qb
        (size_t)N_TOK * KV_SIZE * 2 +     // kb
        (size_t)N_TOK * KV_SIZE * 2 +     // vT
        (size_t)N_TOK * Q_SIZE * 2 +      // og
        (size_t)N_TOK * HQ * 4;           // gate
    if (ws_size < small_bytes) return;    // loud failure: output stays zero

    int* meta = (int*)ws;
    int* perm = (int*)(ws + 64);
    unsigned short* h   = (unsigned short*)(ws + 16384);
    unsigned short* qkv = h   + (size_t)N_TOK * HIDDEN;
    unsigned short* qb  = qkv + (size_t)N_TOK * QKV_OUT;
    unsigned short* kb  = qb  + (size_t)N_TOK * Q_SIZE;
    unsigned short* vT  = kb  + (size_t)N_TOK * KV_SIZE;
    unsigned short* og  = vT  + (size_t)N_TOK * KV_SIZE;
    float* gate = (float*)(og + (size_t)N_TOK * Q_SIZE);

    const int LDS3 = 3 * 49152;  // 144 KiB dynamic
    hipFuncSetAttribute(reinterpret_cast<const void*>(k_gemm<QKV_OUT, false>),
                        hipFuncAttributeMaxDynamicSharedMemorySize, LDS3);
    hipFuncSetAttribute(reinterpret_cast<const void*>(k_gemm<HIDDEN, true>),
                        hipFuncAttributeMaxDynamicSharedMemorySize, LDS3);

    k_sort<<<1, 64, 0, stream>>>(mids, meta, perm);
    k_prenorm<<<2048, 256, 0, stream>>>(hidden, pnw, meta, perm, h);
    k_gemm<QKV_OUT, false><<<8 * 57 * 3, 512, LDS3, stream>>>(
        h, qkvw, qkv, nullptr, meta, perm, 8, 57);
    k_qknorm<<<2048, 256, 0, stream>>>(qkv, rope, qnw, knw, meta, perm, qb, kb, gate);
    k_vtrans<<<dim3(32, 2, 8), 256, 0, stream>>>(qkv, vT);
    k_attn<<<dim3(16, 40), 256, 0, stream>>>(qb, kb, vT, gate, og);
    k_gemm<HIDDEN, true><<<8 * 40 * 3, 512, LDS3, stream>>>(
        og, projw, nullptr, out, meta, perm, 8, 40);
}